// Round 7
// baseline (828.069 us; speedup 1.0000x reference)
//
#include <hip/hip_runtime.h>
#include <hip/hip_bf16.h>
#include <stdint.h>

#define B_     2048
#define WIN_   11
#define K_     4096
#define VOCAB_ 30522
#define NOUT_  18
#define TOPK_  64
#define NPAIR_ (B_ * WIN_)         /* 22528 */
#define PI_F   3.14159274101257324f

#define NCH_    15                 /* chunks per k-slice */
#define CHUNK_  2048               /* entries = 16 KB = 1024 float4 units */
#define UNITS_  1024               /* float4 units per full chunk */
#define UPK_    15261              /* float4 units per k-slice */
#define TAILU_  925                /* units in last chunk */
#define KPB_    16                 /* k per persistent block */
#define NBLK_   (K_ / KPB_)        /* 256 blocks = 1 per CU */
#define GTOT_   (NCH_ * KPB_)      /* 240 phases; % 4 == 0 */
#define PFTH_   1024
#define PROD_   256                /* producer threads (waves 0-3) */
#define CONS_   768                /* consumer threads (waves 4-15) */
#define PCON_BYTES_ (NPAIR_ * 4)                    /* 90112 */
#define SMEM_BYTES_ (PCON_BYTES_ + 4 * CHUNK_ * 8)  /* 155648 (proven) */

static_assert(GTOT_ % 4 == 0, "unroll-4 rotation");

// ---------------------------------------------------------------------------
// Kernel A: per-batch window prep -> cos/sin per (b,w)
// ---------------------------------------------------------------------------
__global__ void prep_kernel(const int* __restrict__ ids, float2* __restrict__ ocs) {
    int b = blockIdx.x * blockDim.x + threadIdx.x;
    if (b >= B_) return;
    const int* row = ids + b * WIN_;
    int poss[WIN_];
    int cnt = 0;
#pragma unroll
    for (int w = 0; w < WIN_; ++w) { cnt += (row[w] != 0); poss[w] = cnt; }
    float fsl = (float)((cnt > 0) ? cnt : WIN_);
#pragma unroll
    for (int w = 0; w < WIN_; ++w) {
        float pos = __fdiv_rn(__fmul_rn(PI_F, (float)poss[w]), fsl);
        float2 o;
        o.x = cosf(pos);
        o.y = sinf(pos);
        ocs[b * WIN_ + w] = o;
    }
}

// ---------------------------------------------------------------------------
// Kernel A2: stable deterministic bucket-by-chunk of the 22528 (b,w) pairs.
// ---------------------------------------------------------------------------
__global__ __launch_bounds__(512) void bucket_kernel(const int* __restrict__ ids,
                                                     const float2* __restrict__ ocs,
                                                     float4* __restrict__ smeta,
                                                     int* __restrict__ chunkstart) {
    __shared__ int lcnt[512 * NCH_];
    __shared__ int segtot[NCH_][8];
    __shared__ int tot[NCH_];
    __shared__ int bbase[NCH_ + 1];
    const int t = threadIdx.x;

#pragma unroll
    for (int c = 0; c < NCH_; ++c) lcnt[t * NCH_ + c] = 0;
    __syncthreads();

    for (int p = t; p < NPAIR_; p += 512) {
        int id = ids[p];
        if (id != 0) lcnt[t * NCH_ + (id / CHUNK_)] += 1;
    }
    __syncthreads();

    if (t < NCH_ * 8) {
        int bkt = t >> 3, seg = t & 7;
        int run = 0;
        for (int i = 0; i < 64; ++i) {
            int idx = (seg * 64 + i) * NCH_ + bkt;
            int tmp = lcnt[idx];
            lcnt[idx] = run;
            run += tmp;
        }
        segtot[bkt][seg] = run;
    }
    __syncthreads();
    if (t < NCH_) {
        int run = 0;
#pragma unroll
        for (int s = 0; s < 8; ++s) { int tmp = segtot[t][s]; segtot[t][s] = run; run += tmp; }
        tot[t] = run;
    }
    __syncthreads();
    if (t == 0) {
        int run = 0;
#pragma unroll
        for (int c = 0; c < NCH_; ++c) { bbase[c] = run; run += tot[c]; }
        bbase[NCH_] = run;
#pragma unroll
        for (int c = 0; c <= NCH_; ++c) chunkstart[c] = bbase[c];
    }
    __syncthreads();
    if (t < NCH_ * 8) {
        int bkt = t >> 3, seg = t & 7;
        int add = segtot[bkt][seg];
        for (int i = 0; i < 64; ++i) lcnt[(seg * 64 + i) * NCH_ + bkt] += add;
    }
    __syncthreads();

    for (int p = t; p < NPAIR_; p += 512) {
        int id = ids[p];
        if (id == 0) continue;
        int bkt = id / CHUNK_;
        int pos = bbase[bkt] + lcnt[t * NCH_ + bkt];
        lcnt[t * NCH_ + bkt] += 1;
        float2 o = ocs[p];
        float4 m;
        m.x = __int_as_float(id);
        m.y = __int_as_float(p);
        m.z = o.x;
        m.w = o.y;
        smeta[pos] = m;
    }
}

// ---------------------------------------------------------------------------
// pair body: bit-identical arithmetic to the passing rounds
// ---------------------------------------------------------------------------
__device__ __forceinline__ void pair_body(const float4 m, const float2* __restrict__ sb,
                                          int lo, float* __restrict__ pcontrib) {
    int id  = __float_as_int(m.x);
    int dst = __float_as_int(m.y);
    float2 g = sb[id - lo];
    float wabs = sqrtf(__fadd_rn(__fmul_rn(g.x, g.x), __fmul_rn(g.y, g.y)));
    float pre = __fadd_rn(__fmul_rn(g.x, m.z), __fmul_rn(g.y, m.w));
    float pim = __fsub_rn(__fmul_rn(g.y, m.z), __fmul_rn(g.x, m.w));
    if (pre < 1e-10f && pre > -1e-10f) pre = 1e-10f;
    if (pim < 1e-10f && pim > -1e-10f) pim = 1e-10f;
    float ang = fabsf(atan2f(pim, pre));
    pcontrib[dst] = __fadd_rn(wabs, ang);
}

// ---------------------------------------------------------------------------
// Kernel B: persistent, 1 block/CU, producer/consumer wave specialization.
// Waves 0-3: W staging only (4-deep reg pipeline; vmcnt queue = W loads only).
// Waves 4-15: smeta prefetch + gather + atan2 (vmcnt queue = smeta only).
// Barriers drain lgkm ONLY; all vmcnt waits are compiler-derived per wave.
// ---------------------------------------------------------------------------
__global__ __launch_bounds__(PFTH_, 1) void pf_kernel(const float4* __restrict__ W4,
                                                      const float4* __restrict__ smeta,
                                                      const int* __restrict__ chunkstart,
                                                      float* __restrict__ pfT) {
    extern __shared__ char smem[];
    float*  pcontrib = (float*)smem;                       // [NPAIR_]
    char*   sbuf     = smem + PCON_BYTES_;                 // [4][16 KB]
    __shared__ int cstart[NCH_ + 1];

    const int t = threadIdx.x;
    const int kbase = blockIdx.x * KPB_;

    if (t <= NCH_) cstart[t] = chunkstart[t];
    __syncthreads();

    float4 s0[4], s1[4], s2[4], s3[4];     // producer 4-deep chunk sets
    float4 A0{}, A1{}, B0{}, B1{};         // consumer smeta ping-pong

    // ---- prologue: buf0 <- chunk 0; producer sets <- chunks 1..3; smeta(ch0)
    {
        const float4* Wb = W4 + (size_t)kbase * UPK_;
        float4 w = Wb[t];                       // chunk 0, 1024 units
        ((float4*)sbuf)[t] = w;                 // compiler-managed vmcnt wait
        if (t < PROD_) {
#pragma unroll
            for (int j = 0; j < 4; ++j) s1[j] = Wb[1 * UNITS_ + j * PROD_ + t];
#pragma unroll
            for (int j = 0; j < 4; ++j) s2[j] = Wb[2 * UNITS_ + j * PROD_ + t];
#pragma unroll
            for (int j = 0; j < 4; ++j) s3[j] = Wb[3 * UNITS_ + j * PROD_ + t];
        } else {
            int ct = t - PROD_;
            int q0 = ct;          if (q0 > NPAIR_ - 1) q0 = NPAIR_ - 1;
            int q1 = CONS_ + ct;  if (q1 > NPAIR_ - 1) q1 = NPAIR_ - 1;
            A0 = smeta[q0];
            A1 = smeta[q1];
        }
        for (int i = t; i < NPAIR_; i += PFTH_) pcontrib[i] = 0.0f;
    }
    asm volatile("s_waitcnt vmcnt(0) lgkmcnt(0)" ::: "memory");
    __builtin_amdgcn_s_barrier();
    __builtin_amdgcn_sched_barrier(0);

#define PHASE(J, SLD, SWR, SU0, SU1, SL0, SL1)                                   \
    {                                                                            \
        const int p_ = g + (J);                                                  \
        __builtin_amdgcn_sched_barrier(0);                                       \
        asm volatile("s_waitcnt lgkmcnt(0)" ::: "memory");                       \
        __builtin_amdgcn_s_barrier();                                            \
        __builtin_amdgcn_sched_barrier(0);                                       \
        int ccj_ = cc + (J); int kkj_ = kk;                                      \
        if (ccj_ >= NCH_) { ccj_ -= NCH_; kkj_ += 1; }                           \
        if (t < PROD_) {                                                         \
            /* ds_write chunk p+1 from SWR (loaded 3 phases ago) */              \
            if (p_ + 1 < GTOT_) {                                                \
                int cwc_ = ccj_ + 1; if (cwc_ >= NCH_) cwc_ = 0;                 \
                int nw_ = (cwc_ == NCH_ - 1) ? TAILU_ : UNITS_;                  \
                float4* dstb_ = (float4*)(sbuf + (size_t)((p_ + 1) & 3) * (CHUNK_ * 8)); \
                _Pragma("unroll")                                                \
                for (int j = 0; j < 4; ++j) {                                    \
                    int u_ = j * PROD_ + t;                                      \
                    if (u_ < nw_) dstb_[u_] = SWR[j];                            \
                }                                                                \
            }                                                                    \
            /* load chunk p+4 into SLD */                                        \
            {   int cl_ = ccj_ + 4; int kl_ = kkj_;                              \
                if (cl_ >= NCH_) { cl_ -= NCH_; kl_ += 1; }                      \
                if (p_ + 4 >= GTOT_) { cl_ = NCH_ - 1; kl_ = KPB_ - 1; }         \
                int nu_ = (cl_ == NCH_ - 1) ? TAILU_ : UNITS_;                   \
                const float4* src_ = W4 + (size_t)(kbase + kl_) * UPK_ + (size_t)cl_ * UNITS_; \
                _Pragma("unroll")                                                \
                for (int j = 0; j < 4; ++j) {                                    \
                    int u_ = j * PROD_ + t;                                      \
                    if (u_ < nu_) SLD[j] = src_[u_];                             \
                }                                                                \
            }                                                                    \
        } else {                                                                 \
            int ct_ = t - PROD_;                                                 \
            /* smeta prefetch for chunk p+1 */                                   \
            {   int cn_ = ccj_ + 1; if (cn_ >= NCH_) cn_ = 0;                    \
                int ns_ = cstart[cn_];                                           \
                int q0_ = ns_ + ct_;          if (q0_ > NPAIR_ - 1) q0_ = NPAIR_ - 1; \
                int q1_ = ns_ + CONS_ + ct_;  if (q1_ > NPAIR_ - 1) q1_ = NPAIR_ - 1; \
                SL0 = smeta[q0_]; SL1 = smeta[q1_]; }                            \
            /* compute chunk p */                                                \
            {   const float2* sb_ = (const float2*)(sbuf + (size_t)(p_ & 3) * (CHUNK_ * 8)); \
                const int lo_ = ccj_ * CHUNK_;                                   \
                const int cs_ = cstart[ccj_], ce_ = cstart[ccj_ + 1];            \
                if (cs_ + ct_ < ce_)          pair_body(SU0, sb_, lo_, pcontrib);\
                if (cs_ + CONS_ + ct_ < ce_)  pair_body(SU1, sb_, lo_, pcontrib);\
                for (int pp_ = cs_ + 2 * CONS_ + ct_; pp_ < ce_; pp_ += CONS_)   \
                    pair_body(smeta[pp_], sb_, lo_, pcontrib); }                 \
        }                                                                        \
        /* k-boundary: sum pcontrib in exact w order -> pfT (all threads) */     \
        if (ccj_ == NCH_ - 1) {                                                  \
            __builtin_amdgcn_sched_barrier(0);                                   \
            asm volatile("s_waitcnt lgkmcnt(0)" ::: "memory");                   \
            __builtin_amdgcn_s_barrier();                                        \
            __builtin_amdgcn_sched_barrier(0);                                   \
            float* outp_ = pfT + (size_t)(kbase + kkj_) * B_;                    \
            _Pragma("unroll")                                                    \
            for (int i_ = 0; i_ < B_ / PFTH_; ++i_) {                            \
                int b_ = i_ * PFTH_ + t;                                         \
                float acc_ = 0.0f;                                               \
                _Pragma("unroll")                                                \
                for (int w_ = 0; w_ < WIN_; ++w_)                                \
                    acc_ = __fadd_rn(acc_, pcontrib[b_ * WIN_ + w_]);            \
                outp_[b_] = acc_;                                                \
            }                                                                    \
        }                                                                        \
    }

#pragma unroll 1
    for (int g = 0; g < GTOT_; g += 4) {
        const int cc = g % NCH_, kk = g / NCH_;
        PHASE(0, s0, s1, A0, A1, B0, B1)
        PHASE(1, s1, s2, B0, B1, A0, A1)
        PHASE(2, s2, s3, A0, A1, B0, B1)
        PHASE(3, s3, s0, B0, B1, A0, A1)
    }
#undef PHASE
}

// ---------------------------------------------------------------------------
// Kernel T: transpose [K,B] -> [B,K] via 64x64 LDS tiles
// ---------------------------------------------------------------------------
__global__ __launch_bounds__(256) void transpose_kb(const float* __restrict__ pfT,
                                                    float* __restrict__ pf) {
    __shared__ float tile[64][65];
    int kb = blockIdx.x * 64;
    int bb = blockIdx.y * 64;
    int tx = threadIdx.x & 63;
    int ty = threadIdx.x >> 6;
#pragma unroll
    for (int i = 0; i < 64; i += 4)
        tile[ty + i][tx] = pfT[(size_t)(kb + ty + i) * B_ + (bb + tx)];
    __syncthreads();
#pragma unroll
    for (int i = 0; i < 64; i += 4)
        pf[(size_t)(bb + ty + i) * K_ + (kb + tx)] = tile[tx][ty + i];
}

// ---------------------------------------------------------------------------
// Kernel C: per-row exact top-64 (radix select, jax tie semantics) + logits
// ---------------------------------------------------------------------------
__global__ __launch_bounds__(256) void topk_logits_kernel(const float* __restrict__ pf,
                                                          const float* __restrict__ w_out,
                                                          const float* __restrict__ b_out,
                                                          float* __restrict__ out) {
    const int b = blockIdx.x;
    const int t = threadIdx.x;
    __shared__ uint32_t srow[K_];
    __shared__ int hist[256];
    __shared__ uint32_t sh_prefix;
    __shared__ int sh_need;
    __shared__ int wave_gt[4], wave_eq[4];
    __shared__ int gt_running, eq_running;
    __shared__ int idxlist[TOPK_];
    __shared__ float partial[4][NOUT_];

    const float* rowp = pf + (size_t)b * K_;
    for (int i = t; i < K_; i += 256) srow[i] = __float_as_uint(rowp[i]);
    if (t == 0) { sh_prefix = 0u; sh_need = TOPK_; gt_running = 0; eq_running = 0; }
    __syncthreads();

    for (int pass = 0; pass < 4; ++pass) {
        int shift = 24 - 8 * pass;
        uint32_t himask = (pass == 0) ? 0u : (0xFFFFFFFFu << (shift + 8));
        hist[t] = 0;
        __syncthreads();
        uint32_t prefix = sh_prefix;
        for (int i = t; i < K_; i += 256) {
            uint32_t u = srow[i];
            if ((u & himask) == prefix) atomicAdd(&hist[(u >> shift) & 255], 1);
        }
        __syncthreads();
        if (t == 0) {
            int need = sh_need, cum = 0, bin = 255;
            for (; bin >= 0; --bin) {
                int c = hist[bin];
                if (cum + c >= need) { sh_need = need - cum; break; }
                cum += c;
            }
            sh_prefix = prefix | ((uint32_t)bin << shift);
        }
        __syncthreads();
    }
    const uint32_t T = sh_prefix;
    const int r = sh_need;
    const int c_gt = TOPK_ - r;

    for (int cbase = 0; cbase < K_; cbase += 256) {
        uint32_t u = srow[cbase + t];
        bool gt = (u > T);
        bool eq = (u == T);
        unsigned long long mg = __ballot(gt);
        unsigned long long me = __ballot(eq);
        int lane = t & 63, wv = t >> 6;
        if (lane == 0) { wave_gt[wv] = __popcll(mg); wave_eq[wv] = __popcll(me); }
        __syncthreads();
        int offg = gt_running, offe = eq_running;
        for (int w2 = 0; w2 < wv; ++w2) { offg += wave_gt[w2]; offe += wave_eq[w2]; }
        unsigned long long lmask = (lane == 0) ? 0ull : ((~0ull) >> (64 - lane));
        int rkg = offg + __popcll(mg & lmask);
        int rke = offe + __popcll(me & lmask);
        if (gt) idxlist[rkg] = cbase + t;
        else if (eq && rke < r) idxlist[c_gt + rke] = cbase + t;
        __syncthreads();
        if (t == 0) {
            gt_running += wave_gt[0] + wave_gt[1] + wave_gt[2] + wave_gt[3];
            eq_running += wave_eq[0] + wave_eq[1] + wave_eq[2] + wave_eq[3];
        }
        __syncthreads();
    }

    {
        int lane = t & 63, wv4 = t >> 6;
        if (lane < NOUT_) {
            const float* wrow = w_out + (size_t)lane * K_;
            float s = 0.0f;
#pragma unroll
            for (int j = 0; j < TOPK_ / 4; ++j) s += wrow[idxlist[wv4 * (TOPK_ / 4) + j]];
            partial[wv4][lane] = s;
        }
        __syncthreads();
        if (t < NOUT_) {
            float s = b_out[t] + partial[0][t] + partial[1][t] + partial[2][t] + partial[3][t];
            out[b * NOUT_ + t] = s;
        }
    }
}

// ---------------------------------------------------------------------------
extern "C" void kernel_launch(void* const* d_in, const int* in_sizes, int n_in,
                              void* d_out, int out_size, void* d_ws, size_t ws_size,
                              hipStream_t stream) {
    const int*   ids   = (const int*)d_in[0];
    const float* W     = (const float*)d_in[1];
    const float* w_out = (const float*)d_in[2];
    const float* b_out = (const float*)d_in[3];
    float* out = (float*)d_out;

    char* ws = (char*)d_ws;
    const size_t pf_bytes = (size_t)K_ * B_ * sizeof(float);   // 33.55 MB
    float*  pfT   = (float*)(ws);                              // [K, B]
    float*  pf    = (float*)(ws + pf_bytes);                   // [B, K]
    float2* ocs   = (float2*)(ws + 2 * pf_bytes);              // [NPAIR_]
    float4* smeta = (float4*)(ws + 2 * pf_bytes + 256 * 1024); // [NPAIR_]
    int* chunkstart = (int*)(ws + 2 * pf_bytes + 768 * 1024);  // [NCH_+1]

    (void)hipFuncSetAttribute((const void*)pf_kernel,
                              hipFuncAttributeMaxDynamicSharedMemorySize,
                              SMEM_BYTES_);

    prep_kernel<<<(B_ + 255) / 256, 256, 0, stream>>>(ids, ocs);
    bucket_kernel<<<1, 512, 0, stream>>>(ids, ocs, smeta, chunkstart);
    pf_kernel<<<NBLK_, PFTH_, SMEM_BYTES_, stream>>>((const float4*)W, smeta, chunkstart, pfT);
    transpose_kb<<<dim3(K_ / 64, B_ / 64), 256, 0, stream>>>(pfT, pf);
    topk_logits_kernel<<<B_, 256, 0, stream>>>(pf, w_out, b_out, out);
}

// Round 8
// 410.241 us; speedup vs baseline: 2.0185x; 2.0185x over previous
//
#include <hip/hip_runtime.h>
#include <hip/hip_bf16.h>
#include <stdint.h>

#define B_     2048
#define WIN_   11
#define K_     4096
#define VOCAB_ 30522
#define NOUT_  18
#define TOPK_  64
#define NPAIR_ (B_ * WIN_)         /* 22528 */
#define PI_F   3.14159274101257324f

#define NCH_    15                 /* chunks per k-slice */
#define CHUNK_  2048               /* entries = 16 KB = 1024 float4 units */
#define UNITS_  1024               /* float4 units per full chunk */
#define UPK_    15261              /* float4 units per k-slice */
#define TAILU_  925                /* units in last chunk */
#define KPB_    16                 /* k per persistent block */
#define NBLK_   (K_ / KPB_)        /* 256 blocks = 1 per CU */
#define GTOT_   (NCH_ * KPB_)      /* 240 phases; % 4 == 0 */
#define PFTH_   1024
#define PROD_   512                /* producer threads (waves 0-7) */
#define CONS_   512                /* consumer threads (waves 8-15) */
#define PCON_BYTES_ (NPAIR_ * 4)                    /* 90112 */
#define SMEM_BYTES_ (PCON_BYTES_ + 4 * CHUNK_ * 8)  /* 155648 (proven) */

static_assert(GTOT_ % 4 == 0, "unroll-4 rotation");

// ---------------------------------------------------------------------------
// Kernel A: per-batch window prep -> cos/sin per (b,w)
// ---------------------------------------------------------------------------
__global__ void prep_kernel(const int* __restrict__ ids, float2* __restrict__ ocs) {
    int b = blockIdx.x * blockDim.x + threadIdx.x;
    if (b >= B_) return;
    const int* row = ids + b * WIN_;
    int poss[WIN_];
    int cnt = 0;
#pragma unroll
    for (int w = 0; w < WIN_; ++w) { cnt += (row[w] != 0); poss[w] = cnt; }
    float fsl = (float)((cnt > 0) ? cnt : WIN_);
#pragma unroll
    for (int w = 0; w < WIN_; ++w) {
        float pos = __fdiv_rn(__fmul_rn(PI_F, (float)poss[w]), fsl);
        float2 o;
        o.x = cosf(pos);
        o.y = sinf(pos);
        ocs[b * WIN_ + w] = o;
    }
}

// ---------------------------------------------------------------------------
// Kernel A2: stable deterministic bucket-by-chunk of the 22528 (b,w) pairs.
// ---------------------------------------------------------------------------
__global__ __launch_bounds__(512) void bucket_kernel(const int* __restrict__ ids,
                                                     const float2* __restrict__ ocs,
                                                     float4* __restrict__ smeta,
                                                     int* __restrict__ chunkstart) {
    __shared__ int lcnt[512 * NCH_];
    __shared__ int segtot[NCH_][8];
    __shared__ int tot[NCH_];
    __shared__ int bbase[NCH_ + 1];
    const int t = threadIdx.x;

#pragma unroll
    for (int c = 0; c < NCH_; ++c) lcnt[t * NCH_ + c] = 0;
    __syncthreads();

    for (int p = t; p < NPAIR_; p += 512) {
        int id = ids[p];
        if (id != 0) lcnt[t * NCH_ + (id / CHUNK_)] += 1;
    }
    __syncthreads();

    if (t < NCH_ * 8) {
        int bkt = t >> 3, seg = t & 7;
        int run = 0;
        for (int i = 0; i < 64; ++i) {
            int idx = (seg * 64 + i) * NCH_ + bkt;
            int tmp = lcnt[idx];
            lcnt[idx] = run;
            run += tmp;
        }
        segtot[bkt][seg] = run;
    }
    __syncthreads();
    if (t < NCH_) {
        int run = 0;
#pragma unroll
        for (int s = 0; s < 8; ++s) { int tmp = segtot[t][s]; segtot[t][s] = run; run += tmp; }
        tot[t] = run;
    }
    __syncthreads();
    if (t == 0) {
        int run = 0;
#pragma unroll
        for (int c = 0; c < NCH_; ++c) { bbase[c] = run; run += tot[c]; }
        bbase[NCH_] = run;
#pragma unroll
        for (int c = 0; c <= NCH_; ++c) chunkstart[c] = bbase[c];
    }
    __syncthreads();
    if (t < NCH_ * 8) {
        int bkt = t >> 3, seg = t & 7;
        int add = segtot[bkt][seg];
        for (int i = 0; i < 64; ++i) lcnt[(seg * 64 + i) * NCH_ + bkt] += add;
    }
    __syncthreads();

    for (int p = t; p < NPAIR_; p += 512) {
        int id = ids[p];
        if (id == 0) continue;
        int bkt = id / CHUNK_;
        int pos = bbase[bkt] + lcnt[t * NCH_ + bkt];
        lcnt[t * NCH_ + bkt] += 1;
        float2 o = ocs[p];
        float4 m;
        m.x = __int_as_float(id);
        m.y = __int_as_float(p);
        m.z = o.x;
        m.w = o.y;
        smeta[pos] = m;
    }
}

// ---------------------------------------------------------------------------
// pair body: bit-identical arithmetic to the passing rounds
// ---------------------------------------------------------------------------
__device__ __forceinline__ void pair_body(const float4 m, const float2* __restrict__ sb,
                                          int lo, float* __restrict__ pcontrib) {
    int id  = __float_as_int(m.x);
    int dst = __float_as_int(m.y);
    float2 g = sb[id - lo];
    float wabs = sqrtf(__fadd_rn(__fmul_rn(g.x, g.x), __fmul_rn(g.y, g.y)));
    float pre = __fadd_rn(__fmul_rn(g.x, m.z), __fmul_rn(g.y, m.w));
    float pim = __fsub_rn(__fmul_rn(g.y, m.z), __fmul_rn(g.x, m.w));
    if (pre < 1e-10f && pre > -1e-10f) pre = 1e-10f;
    if (pim < 1e-10f && pim > -1e-10f) pim = 1e-10f;
    float ang = fabsf(atan2f(pim, pre));
    pcontrib[dst] = __fadd_rn(wabs, ang);
}

// ---------------------------------------------------------------------------
// Kernel B: persistent, 1 block/CU, producer/consumer wave specialization.
// Waves 0-7 (512 thr): W staging only — 4-deep pipeline in NAMED float4 regs
// (p0a..p3b; no arrays -> no scratch). Waves 8-15 (512 thr): smeta prefetch
// (3 named regs per ping-pong set) + gather + atan2. Barriers drain lgkm only.
// ---------------------------------------------------------------------------
__global__ __launch_bounds__(PFTH_, 1) void pf_kernel(const float4* __restrict__ W4,
                                                      const float4* __restrict__ smeta,
                                                      const int* __restrict__ chunkstart,
                                                      float* __restrict__ pfT) {
    extern __shared__ char smem[];
    float*  pcontrib = (float*)smem;                       // [NPAIR_]
    char*   sbuf     = smem + PCON_BYTES_;                 // [4][16 KB]
    __shared__ int cstart[NCH_ + 1];

    const int t = threadIdx.x;
    const int kbase = blockIdx.x * KPB_;
    const float4* Wb = W4 + (size_t)kbase * UPK_;

    if (t <= NCH_) cstart[t] = chunkstart[t];
    __syncthreads();

    // producer staged chunks: set i holds chunk (phase where phase&3==i)+... 2 units each
    float4 p0a, p0b, p1a, p1b, p2a, p2b, p3a, p3b;
    // consumer smeta ping-pong sets (3 regs each cover 1536 pairs; tail loop rare)
    float4 A0{}, A1{}, A2{}, B0{}, B1{}, B2{};

    // ---- prologue: buf0 <- chunk 0 (direct); sets 1..3 <- chunks 1..3; smeta ch0 -> A
    {
        ((float4*)sbuf)[t] = Wb[t];             // chunk 0 is always full
        if (t < PROD_) {
            p1a = Wb[1 * UNITS_ + t];  p1b = Wb[1 * UNITS_ + PROD_ + t];
            p2a = Wb[2 * UNITS_ + t];  p2b = Wb[2 * UNITS_ + PROD_ + t];
            p3a = Wb[3 * UNITS_ + t];  p3b = Wb[3 * UNITS_ + PROD_ + t];
        } else {
            int ct = t - PROD_;
            int q0 = ct;               if (q0 > NPAIR_ - 1) q0 = NPAIR_ - 1;
            int q1 = CONS_ + ct;       if (q1 > NPAIR_ - 1) q1 = NPAIR_ - 1;
            int q2 = 2 * CONS_ + ct;   if (q2 > NPAIR_ - 1) q2 = NPAIR_ - 1;
            A0 = smeta[q0]; A1 = smeta[q1]; A2 = smeta[q2];
        }
        for (int i = t; i < NPAIR_; i += PFTH_) pcontrib[i] = 0.0f;
    }
    asm volatile("s_waitcnt vmcnt(0) lgkmcnt(0)" ::: "memory");
    __builtin_amdgcn_s_barrier();
    __builtin_amdgcn_sched_barrier(0);

#define PHASE(J, LDa, LDb, WRa, WRb, SU0, SU1, SU2, SL0, SL1, SL2)               \
    {                                                                            \
        const int p_ = g + (J);                                                  \
        __builtin_amdgcn_sched_barrier(0);                                       \
        asm volatile("s_waitcnt lgkmcnt(0)" ::: "memory");                       \
        __builtin_amdgcn_s_barrier();                                            \
        __builtin_amdgcn_sched_barrier(0);                                       \
        int ccj_ = cc + (J); int kkj_ = kk;                                      \
        if (ccj_ >= NCH_) { ccj_ -= NCH_; kkj_ += 1; }                           \
        if (t < PROD_) {                                                         \
            /* ds_write chunk p+1 from regs loaded 3 phases ago */               \
            if (p_ + 1 < GTOT_) {                                                \
                int cwc_ = ccj_ + 1; if (cwc_ >= NCH_) cwc_ = 0;                 \
                int nw_ = (cwc_ == NCH_ - 1) ? TAILU_ : UNITS_;                  \
                float4* dstb_ = (float4*)(sbuf + (size_t)((p_ + 1) & 3) * (CHUNK_ * 8)); \
                if (t < nw_)         dstb_[t] = WRa;                             \
                if (PROD_ + t < nw_) dstb_[PROD_ + t] = WRb;                     \
            }                                                                    \
            /* load chunk p+4 into (LDa, LDb) */                                 \
            {   int cl_ = ccj_ + 4; int kl_ = kkj_;                              \
                if (cl_ >= NCH_) { cl_ -= NCH_; kl_ += 1; }                      \
                if (p_ + 4 >= GTOT_) { cl_ = NCH_ - 1; kl_ = KPB_ - 1; }         \
                int nu_ = (cl_ == NCH_ - 1) ? TAILU_ : UNITS_;                   \
                const float4* src_ = W4 + (size_t)(kbase + kl_) * UPK_ + (size_t)cl_ * UNITS_; \
                if (t < nu_)         LDa = src_[t];                              \
                if (PROD_ + t < nu_) LDb = src_[PROD_ + t];                      \
            }                                                                    \
        } else {                                                                 \
            int ct_ = t - PROD_;                                                 \
            /* smeta prefetch for chunk p+1 */                                   \
            {   int cn_ = ccj_ + 1; if (cn_ >= NCH_) cn_ = 0;                    \
                int ns_ = cstart[cn_];                                           \
                int q0_ = ns_ + ct_;             if (q0_ > NPAIR_ - 1) q0_ = NPAIR_ - 1; \
                int q1_ = ns_ + CONS_ + ct_;     if (q1_ > NPAIR_ - 1) q1_ = NPAIR_ - 1; \
                int q2_ = ns_ + 2 * CONS_ + ct_; if (q2_ > NPAIR_ - 1) q2_ = NPAIR_ - 1; \
                SL0 = smeta[q0_]; SL1 = smeta[q1_]; SL2 = smeta[q2_]; }          \
            /* compute chunk p */                                                \
            {   const float2* sb_ = (const float2*)(sbuf + (size_t)(p_ & 3) * (CHUNK_ * 8)); \
                const int lo_ = ccj_ * CHUNK_;                                   \
                const int cs_ = cstart[ccj_], ce_ = cstart[ccj_ + 1];            \
                if (cs_ + ct_ < ce_)             pair_body(SU0, sb_, lo_, pcontrib); \
                if (cs_ + CONS_ + ct_ < ce_)     pair_body(SU1, sb_, lo_, pcontrib); \
                if (cs_ + 2 * CONS_ + ct_ < ce_) pair_body(SU2, sb_, lo_, pcontrib); \
                for (int pp_ = cs_ + 3 * CONS_ + ct_; pp_ < ce_; pp_ += CONS_)   \
                    pair_body(smeta[pp_], sb_, lo_, pcontrib); }                 \
        }                                                                        \
        /* k-boundary: sum pcontrib in exact w order -> pfT (all threads) */     \
        if (ccj_ == NCH_ - 1) {                                                  \
            __builtin_amdgcn_sched_barrier(0);                                   \
            asm volatile("s_waitcnt lgkmcnt(0)" ::: "memory");                   \
            __builtin_amdgcn_s_barrier();                                        \
            __builtin_amdgcn_sched_barrier(0);                                   \
            float* outp_ = pfT + (size_t)(kbase + kkj_) * B_;                    \
            _Pragma("unroll")                                                    \
            for (int i_ = 0; i_ < B_ / PFTH_; ++i_) {                            \
                int b_ = i_ * PFTH_ + t;                                         \
                float acc_ = 0.0f;                                               \
                _Pragma("unroll")                                                \
                for (int w_ = 0; w_ < WIN_; ++w_)                                \
                    acc_ = __fadd_rn(acc_, pcontrib[b_ * WIN_ + w_]);            \
                outp_[b_] = acc_;                                                \
            }                                                                    \
        }                                                                        \
    }

#pragma unroll 1
    for (int g = 0; g < GTOT_; g += 4) {
        const int cc = g % NCH_, kk = g / NCH_;
        PHASE(0, p0a, p0b, p1a, p1b, A0, A1, A2, B0, B1, B2)
        PHASE(1, p1a, p1b, p2a, p2b, B0, B1, B2, A0, A1, A2)
        PHASE(2, p2a, p2b, p3a, p3b, A0, A1, A2, B0, B1, B2)
        PHASE(3, p3a, p3b, p0a, p0b, B0, B1, B2, A0, A1, A2)
    }
#undef PHASE
}

// ---------------------------------------------------------------------------
// Kernel T: transpose [K,B] -> [B,K] via 64x64 LDS tiles
// ---------------------------------------------------------------------------
__global__ __launch_bounds__(256) void transpose_kb(const float* __restrict__ pfT,
                                                    float* __restrict__ pf) {
    __shared__ float tile[64][65];
    int kb = blockIdx.x * 64;
    int bb = blockIdx.y * 64;
    int tx = threadIdx.x & 63;
    int ty = threadIdx.x >> 6;
#pragma unroll
    for (int i = 0; i < 64; i += 4)
        tile[ty + i][tx] = pfT[(size_t)(kb + ty + i) * B_ + (bb + tx)];
    __syncthreads();
#pragma unroll
    for (int i = 0; i < 64; i += 4)
        pf[(size_t)(bb + ty + i) * K_ + (kb + tx)] = tile[tx][ty + i];
}

// ---------------------------------------------------------------------------
// Kernel C: per-row exact top-64 (radix select, jax tie semantics) + logits.
// Bin selection now via parallel suffix-scan (was t==0 serial 256-bin scan).
// ---------------------------------------------------------------------------
__global__ __launch_bounds__(256) void topk_logits_kernel(const float* __restrict__ pf,
                                                          const float* __restrict__ w_out,
                                                          const float* __restrict__ b_out,
                                                          float* __restrict__ out) {
    const int b = blockIdx.x;
    const int t = threadIdx.x;
    __shared__ uint32_t srow[K_];
    __shared__ int hist[256];
    __shared__ int sfx[256];
    __shared__ uint32_t sh_prefix;
    __shared__ int sh_need;
    __shared__ int wave_gt[4], wave_eq[4];
    __shared__ int gt_running, eq_running;
    __shared__ int idxlist[TOPK_];
    __shared__ float partial[4][NOUT_];

    const float* rowp = pf + (size_t)b * K_;
    for (int i = t; i < K_; i += 256) srow[i] = __float_as_uint(rowp[i]);
    if (t == 0) { sh_prefix = 0u; sh_need = TOPK_; gt_running = 0; eq_running = 0; }
    __syncthreads();

    for (int pass = 0; pass < 4; ++pass) {
        int shift = 24 - 8 * pass;
        uint32_t himask = (pass == 0) ? 0u : (0xFFFFFFFFu << (shift + 8));
        hist[t] = 0;
        __syncthreads();
        uint32_t prefix = sh_prefix & himask;
        for (int i = t; i < K_; i += 256) {
            uint32_t u = srow[i];
            if ((u & himask) == prefix) atomicAdd(&hist[(u >> shift) & 255], 1);
        }
        __syncthreads();
        // parallel suffix scan: sfx[b] = sum_{i>=b} hist[i]
        sfx[t] = hist[t];
        __syncthreads();
#pragma unroll
        for (int off = 1; off < 256; off <<= 1) {
            int v = (t + off < 256) ? sfx[t + off] : 0;
            __syncthreads();
            sfx[t] += v;
            __syncthreads();
        }
        int need = sh_need;
        int above = (t == 255) ? 0 : sfx[t + 1];
        if (sfx[t] >= need && above < need) {      // exactly one bin qualifies
            sh_prefix |= ((uint32_t)t << shift);
            sh_need = need - above;
        }
        __syncthreads();
    }
    const uint32_t T = sh_prefix;
    const int r = sh_need;
    const int c_gt = TOPK_ - r;

    for (int cbase = 0; cbase < K_; cbase += 256) {
        uint32_t u = srow[cbase + t];
        bool gt = (u > T);
        bool eq = (u == T);
        unsigned long long mg = __ballot(gt);
        unsigned long long me = __ballot(eq);
        int lane = t & 63, wv = t >> 6;
        if (lane == 0) { wave_gt[wv] = __popcll(mg); wave_eq[wv] = __popcll(me); }
        __syncthreads();
        int offg = gt_running, offe = eq_running;
        for (int w2 = 0; w2 < wv; ++w2) { offg += wave_gt[w2]; offe += wave_eq[w2]; }
        unsigned long long lmask = (lane == 0) ? 0ull : ((~0ull) >> (64 - lane));
        int rkg = offg + __popcll(mg & lmask);
        int rke = offe + __popcll(me & lmask);
        if (gt) idxlist[rkg] = cbase + t;
        else if (eq && rke < r) idxlist[c_gt + rke] = cbase + t;
        __syncthreads();
        if (t == 0) {
            gt_running += wave_gt[0] + wave_gt[1] + wave_gt[2] + wave_gt[3];
            eq_running += wave_eq[0] + wave_eq[1] + wave_eq[2] + wave_eq[3];
        }
        __syncthreads();
    }

    {
        int lane = t & 63, wv4 = t >> 6;
        if (lane < NOUT_) {
            const float* wrow = w_out + (size_t)lane * K_;
            float s = 0.0f;
#pragma unroll
            for (int j = 0; j < TOPK_ / 4; ++j) s += wrow[idxlist[wv4 * (TOPK_ / 4) + j]];
            partial[wv4][lane] = s;
        }
        __syncthreads();
        if (t < NOUT_) {
            float s = b_out[t] + partial[0][t] + partial[1][t] + partial[2][t] + partial[3][t];
            out[b * NOUT_ + t] = s;
        }
    }
}

// ---------------------------------------------------------------------------
extern "C" void kernel_launch(void* const* d_in, const int* in_sizes, int n_in,
                              void* d_out, int out_size, void* d_ws, size_t ws_size,
                              hipStream_t stream) {
    const int*   ids   = (const int*)d_in[0];
    const float* W     = (const float*)d_in[1];
    const float* w_out = (const float*)d_in[2];
    const float* b_out = (const float*)d_in[3];
    float* out = (float*)d_out;

    char* ws = (char*)d_ws;
    const size_t pf_bytes = (size_t)K_ * B_ * sizeof(float);   // 33.55 MB
    float*  pfT   = (float*)(ws);                              // [K, B]
    float*  pf    = (float*)(ws + pf_bytes);                   // [B, K]
    float2* ocs   = (float2*)(ws + 2 * pf_bytes);              // [NPAIR_]
    float4* smeta = (float4*)(ws + 2 * pf_bytes + 256 * 1024); // [NPAIR_]
    int* chunkstart = (int*)(ws + 2 * pf_bytes + 768 * 1024);  // [NCH_+1]

    (void)hipFuncSetAttribute((const void*)pf_kernel,
                              hipFuncAttributeMaxDynamicSharedMemorySize,
                              SMEM_BYTES_);

    prep_kernel<<<(B_ + 255) / 256, 256, 0, stream>>>(ids, ocs);
    bucket_kernel<<<1, 512, 0, stream>>>(ids, ocs, smeta, chunkstart);
    pf_kernel<<<NBLK_, PFTH_, SMEM_BYTES_, stream>>>((const float4*)W, smeta, chunkstart, pfT);
    transpose_kb<<<dim3(K_ / 64, B_ / 64), 256, 0, stream>>>(pfT, pf);
    topk_logits_kernel<<<B_, 256, 0, stream>>>(pf, w_out, b_out, out);
}